// Round 1
// baseline (1465.187 us; speedup 1.0000x reference)
//
#include <hip/hip_runtime.h>

typedef unsigned short u16;
typedef unsigned int u32;
typedef __bf16 bf16x8 __attribute__((ext_vector_type(8)));
typedef float f32x4 __attribute__((ext_vector_type(4)));

#define DIM 4096
#define NH 32
#define NKV 8
#define HD 128
#define SEQ 2048
#define BATCH 2

__device__ __forceinline__ u16 f2bf(float f) {
  u32 u = __float_as_uint(f);
  u += 0x7fffu + ((u >> 16) & 1u);
  return (u16)(u >> 16);
}
__device__ __forceinline__ float bf2f(u16 b) {
  return __uint_as_float(((u32)b) << 16);
}

__device__ __forceinline__ void async16(void* lds, const void* g) {
  __builtin_amdgcn_global_load_lds(
      (__attribute__((address_space(1))) void*)(g),
      (__attribute__((address_space(3))) void*)(lds), 16, 0, 0);
}

// ---------------- cast fp32 -> bf16 ----------------
__global__ __launch_bounds__(256) void cast_kernel(const float* __restrict__ in,
                                                   u16* __restrict__ out, int n4) {
  int i = blockIdx.x * 256 + threadIdx.x;
  if (i >= n4) return;
  float4 v = ((const float4*)in)[i];
  uint2 o;
  o.x = (u32)f2bf(v.x) | ((u32)f2bf(v.y) << 16);
  o.y = (u32)f2bf(v.z) | ((u32)f2bf(v.w) << 16);
  ((uint2*)out)[i] = o;
}

// ---------------- GEMM: C[M,N] = A[M,K] * B[N,K]^T  (m97 structure) ----------------
template <bool BF16OUT>
__global__ __launch_bounds__(256) void gemm_bt(const u16* __restrict__ A,
                                               const u16* __restrict__ B,
                                               void* __restrict__ Cv,
                                               int M, int N, int K) {
  __shared__ __align__(16) u16 As[128 * 32];
  __shared__ __align__(16) u16 Bs[128 * 32];
  const int tid = threadIdx.x;
  const int w = tid >> 6, l = tid & 63;
  const int wr = w >> 1, wc = w & 1;
  const int bm = blockIdx.x, bn = blockIdx.y;
  f32x4 acc[4][4] = {};
  const u16* Ab = A + (size_t)bm * 128 * K;
  const u16* Bb = B + (size_t)bn * 128 * K;
  const int lrow = l >> 2, lcol = (l & 3) * 8;

  for (int k0 = 0; k0 < K; k0 += 32) {
    __syncthreads();
#pragma unroll
    for (int i = 0; i < 2; ++i) {
      const int rbase = i * 64 + w * 16;
      async16(&As[rbase * 32], Ab + (size_t)(rbase + lrow) * K + k0 + lcol);
      async16(&Bs[rbase * 32], Bb + (size_t)(rbase + lrow) * K + k0 + lcol);
    }
    __syncthreads();
    bf16x8 af[4], bfv[4];
#pragma unroll
    for (int mi = 0; mi < 4; ++mi)
      af[mi] = *(const bf16x8*)&As[(wr * 64 + mi * 16 + (l & 15)) * 32 + (l >> 4) * 8];
#pragma unroll
    for (int ni = 0; ni < 4; ++ni)
      bfv[ni] = *(const bf16x8*)&Bs[(wc * 64 + ni * 16 + (l & 15)) * 32 + (l >> 4) * 8];
#pragma unroll
    for (int mi = 0; mi < 4; ++mi)
#pragma unroll
      for (int ni = 0; ni < 4; ++ni)
        acc[mi][ni] = __builtin_amdgcn_mfma_f32_16x16x32_bf16(af[mi], bfv[ni], acc[mi][ni], 0, 0, 0);
  }
#pragma unroll
  for (int mi = 0; mi < 4; ++mi)
#pragma unroll
    for (int ni = 0; ni < 4; ++ni)
#pragma unroll
      for (int r = 0; r < 4; ++r) {
        int row = bm * 128 + wr * 64 + mi * 16 + (l >> 4) * 4 + r;
        int col = bn * 128 + wc * 64 + ni * 16 + (l & 15);
        float v = acc[mi][ni][r];
        if (BF16OUT)
          ((u16*)Cv)[(size_t)row * N + col] = f2bf(v);
        else
          ((float*)Cv)[(size_t)row * N + col] = v;
      }
}

// ---------------- RoPE (in-place on bf16 buffer, layout [B*S][nh*128]) ----------------
__global__ __launch_bounds__(256) void rope_kernel(u16* __restrict__ buf,
                                                   const float* __restrict__ fc,
                                                   const float* __restrict__ fs,
                                                   const int* __restrict__ spp,
                                                   int nh, int total) {
  int t = blockIdx.x * 256 + threadIdx.x;
  if (t >= total) return;
  int i = t & 63;
  int h = (t >> 6) % nh;
  int s = ((t >> 6) / nh) % SEQ;
  int b = t / (64 * nh * SEQ);
  int pos = spp[0] + s;
  float c = fc[pos * 64 + i], sn = fs[pos * 64 + i];
  u16* p = buf + ((size_t)(b * SEQ + s) * nh + h) * HD + 2 * i;
  u32 both = *(u32*)p;
  float xr = bf2f((u16)(both & 0xffffu));
  float xi = bf2f((u16)(both >> 16));
  float orr = xr * c - xi * sn;
  float oi = xr * sn + xi * c;
  *(u32*)p = (u32)f2bf(orr) | ((u32)f2bf(oi) << 16);
}

// ---------------- Flash attention (causal, GQA) ----------------
// grid: x = S/64 q-tiles, y = H, z = B. 256 threads = 4 waves, wave w owns 16 q rows.
__device__ __forceinline__ int swz(int row, int colel) {
  int byte = (row << 8) + (colel << 1);
  byte ^= (row & 7) << 4;
  return byte >> 1;
}

__global__ __launch_bounds__(256) void attn_kernel(const u16* __restrict__ qb,
                                                   const u16* __restrict__ kb,
                                                   const u16* __restrict__ vb,
                                                   u16* __restrict__ ob,
                                                   const int* __restrict__ spp) {
  const int qt = blockIdx.x, h = blockIdx.y, b = blockIdx.z;
  const int kvh = h >> 2;
  const int tid = threadIdx.x, w = tid >> 6, l = tid & 63;
  const int sp = spp[0];
  __shared__ __align__(16) u16 Kl[32 * 128];
  __shared__ __align__(16) u16 Vl[32 * 128];
  __shared__ __align__(16) u16 Pl[4][16 * 32];
  const int qs = qt * 64;
  const int wq0 = qs + w * 16;

  bf16x8 qf[4];
  const u16* qrow = qb + (size_t)(b * SEQ + wq0 + (l & 15)) * DIM + h * HD;
#pragma unroll
  for (int kk = 0; kk < 4; ++kk)
    qf[kk] = *(const bf16x8*)(qrow + kk * 32 + (l >> 4) * 8);

  f32x4 acc[8] = {};
  float mst[4] = {-1e30f, -1e30f, -1e30f, -1e30f};
  float lst[4] = {0.f, 0.f, 0.f, 0.f};
  const int nt = qs / 32 + 2;

  for (int t = 0; t < nt; ++t) {
    const int t0 = t * 32;
    __syncthreads();
    for (int c = tid; c < 512; c += 256) {
      int row = c >> 4, col = (c & 15) * 8;
      size_t goff = (size_t)(b * SEQ + t0 + row) * (NKV * HD) + kvh * HD + col;
      *(int4*)&Kl[swz(row, col)] = *(const int4*)(kb + goff);
      *(int4*)&Vl[swz(row, col)] = *(const int4*)(vb + goff);
    }
    __syncthreads();

    float sv[2][4];
#pragma unroll
    for (int tt = 0; tt < 2; ++tt) {
      f32x4 sacc = {};
#pragma unroll
      for (int kk = 0; kk < 4; ++kk) {
        bf16x8 kf = *(const bf16x8*)&Kl[swz(tt * 16 + (l & 15), kk * 32 + (l >> 4) * 8)];
        sacc = __builtin_amdgcn_mfma_f32_16x16x32_bf16(qf[kk], kf, sacc, 0, 0, 0);
      }
#pragma unroll
      for (int r = 0; r < 4; ++r) {
        int qrow_s = wq0 + (l >> 4) * 4 + r;
        int tg = t0 + tt * 16 + (l & 15);
        float v = sacc[r] * 0.08838834764831845f;
        sv[tt][r] = (tg <= sp + qrow_s) ? v : -1e9f;
      }
    }
    float pm[4];
#pragma unroll
    for (int r = 0; r < 4; ++r) pm[r] = fmaxf(sv[0][r], sv[1][r]);
#pragma unroll
    for (int off = 1; off < 16; off <<= 1)
#pragma unroll
      for (int r = 0; r < 4; ++r) pm[r] = fmaxf(pm[r], __shfl_xor(pm[r], off));

    float esc[4];
#pragma unroll
    for (int r = 0; r < 4; ++r) {
      float mn = fmaxf(mst[r], pm[r]);
      esc[r] = __expf(mst[r] - mn);
      mst[r] = mn;
    }
    float p[2][4];
#pragma unroll
    for (int tt = 0; tt < 2; ++tt)
#pragma unroll
      for (int r = 0; r < 4; ++r) p[tt][r] = __expf(sv[tt][r] - mst[r]);
    float rs[4];
#pragma unroll
    for (int r = 0; r < 4; ++r) rs[r] = p[0][r] + p[1][r];
#pragma unroll
    for (int off = 1; off < 16; off <<= 1)
#pragma unroll
      for (int r = 0; r < 4; ++r) rs[r] += __shfl_xor(rs[r], off);
#pragma unroll
    for (int r = 0; r < 4; ++r) lst[r] = lst[r] * esc[r] + rs[r];
#pragma unroll
    for (int dc = 0; dc < 8; ++dc)
#pragma unroll
      for (int r = 0; r < 4; ++r) acc[dc][r] *= esc[r];

    // P -> LDS (D-layout) then read back in A-layout
#pragma unroll
    for (int tt = 0; tt < 2; ++tt)
#pragma unroll
      for (int r = 0; r < 4; ++r)
        Pl[w][((l >> 4) * 4 + r) * 32 + tt * 16 + (l & 15)] = f2bf(p[tt][r]);
    bf16x8 pf = *(const bf16x8*)&Pl[w][(l & 15) * 32 + (l >> 4) * 8];

#pragma unroll
    for (int dc = 0; dc < 8; ++dc) {
      union { u16 u[8]; bf16x8 v; } uv;
#pragma unroll
      for (int j = 0; j < 8; ++j)
        uv.u[j] = Vl[swz((l >> 4) * 8 + j, dc * 16 + (l & 15))];
      acc[dc] = __builtin_amdgcn_mfma_f32_16x16x32_bf16(pf, uv.v, acc[dc], 0, 0, 0);
    }
  }
  // epilogue
#pragma unroll
  for (int r = 0; r < 4; ++r) {
    float inv = 1.0f / lst[r];
    size_t rowoff = (size_t)(b * SEQ + wq0 + (l >> 4) * 4 + r) * DIM + h * HD;
#pragma unroll
    for (int dc = 0; dc < 8; ++dc)
      ob[rowoff + dc * 16 + (l & 15)] = f2bf(acc[dc][r] * inv);
  }
}

extern "C" void kernel_launch(void* const* d_in, const int* in_sizes, int n_in,
                              void* d_out, int out_size, void* d_ws, size_t ws_size,
                              hipStream_t stream) {
  (void)in_sizes; (void)n_in; (void)out_size; (void)ws_size;
  const float* x  = (const float*)d_in[0];
  const float* wq = (const float*)d_in[1];
  const float* wk = (const float*)d_in[2];
  const float* wv = (const float*)d_in[3];
  const float* wo = (const float*)d_in[4];
  const float* fc = (const float*)d_in[5];
  const float* fs = (const float*)d_in[6];
  const int* sp   = (const int*)d_in[9];

  char* ws = (char*)d_ws;
  size_t off = 0;
  auto alloc = [&](size_t bytes) {
    void* p = ws + off;
    off += (bytes + 255) & ~(size_t)255;
    return p;
  };
  u16* xb   = (u16*)alloc(16777216ull * 2);  // x bf16 (also reused as attn-out)
  u16* wqb  = (u16*)alloc(16777216ull * 2);
  u16* wkb  = (u16*)alloc(4194304ull * 2);
  u16* wvb  = (u16*)alloc(4194304ull * 2);
  u16* wob  = (u16*)alloc(16777216ull * 2);
  u16* qbuf = (u16*)alloc(16777216ull * 2);
  u16* kbuf = (u16*)alloc(4194304ull * 2);
  u16* vbuf = (u16*)alloc(4194304ull * 2);
  u16* abuf = xb;  // alias: xb dead after QKV GEMMs

  auto cast = [&](const float* in, u16* out, size_t n) {
    int n4 = (int)(n / 4);
    cast_kernel<<<(n4 + 255) / 256, 256, 0, stream>>>(in, out, n4);
  };
  cast(x,  xb,  16777216ull);
  cast(wq, wqb, 16777216ull);
  cast(wk, wkb, 4194304ull);
  cast(wv, wvb, 4194304ull);
  cast(wo, wob, 16777216ull);

  gemm_bt<true><<<dim3(32, 32), 256, 0, stream>>>(xb, wqb, qbuf, 4096, 4096, 4096);
  gemm_bt<true><<<dim3(32, 8), 256, 0, stream>>>(xb, wkb, kbuf, 4096, 1024, 4096);
  gemm_bt<true><<<dim3(32, 8), 256, 0, stream>>>(xb, wvb, vbuf, 4096, 1024, 4096);

  rope_kernel<<<8388608 / 256, 256, 0, stream>>>(qbuf, fc, fs, sp, NH, 8388608);
  rope_kernel<<<2097152 / 256, 256, 0, stream>>>(kbuf, fc, fs, sp, NKV, 2097152);

  attn_kernel<<<dim3(32, 32, 2), 256, 0, stream>>>(qbuf, kbuf, vbuf, abuf, sp);

  gemm_bt<false><<<dim3(32, 32), 256, 0, stream>>>(abuf, wob, d_out, 4096, 4096, 4096);
}

// Round 2
// 1294.591 us; speedup vs baseline: 1.1318x; 1.1318x over previous
//
#include <hip/hip_runtime.h>

typedef unsigned short u16;
typedef unsigned int u32;
typedef __bf16 bf16x8 __attribute__((ext_vector_type(8)));
typedef float f32x4 __attribute__((ext_vector_type(4)));

#define DIM 4096
#define NH 32
#define NKV 8
#define HD 128
#define SEQ 2048
#define BATCH 2

__device__ __forceinline__ u16 f2bf(float f) {
  u32 u = __float_as_uint(f);
  u += 0x7fffu + ((u >> 16) & 1u);
  return (u16)(u >> 16);
}
__device__ __forceinline__ float bf2f(u16 b) {
  return __uint_as_float(((u32)b) << 16);
}

__device__ __forceinline__ void async16(void* lds, const void* g) {
  __builtin_amdgcn_global_load_lds(
      (__attribute__((address_space(1))) void*)(g),
      (__attribute__((address_space(3))) void*)(lds), 16, 0, 0);
}

// ---------------- cast fp32 -> bf16 ----------------
__global__ __launch_bounds__(256) void cast_kernel(const float* __restrict__ in,
                                                   u16* __restrict__ out, int n4) {
  int i = blockIdx.x * 256 + threadIdx.x;
  if (i >= n4) return;
  float4 v = ((const float4*)in)[i];
  uint2 o;
  o.x = (u32)f2bf(v.x) | ((u32)f2bf(v.y) << 16);
  o.y = (u32)f2bf(v.z) | ((u32)f2bf(v.w) << 16);
  ((uint2*)out)[i] = o;
}

// ---------------- GEMM: C[M,N] = A[M,K] * B[N,K]^T  (m97 structure) ----------------
template <bool BF16OUT>
__global__ __launch_bounds__(256) void gemm_bt(const u16* __restrict__ A,
                                               const u16* __restrict__ B,
                                               void* __restrict__ Cv,
                                               int M, int N, int K) {
  __shared__ __align__(16) u16 As[128 * 32];
  __shared__ __align__(16) u16 Bs[128 * 32];
  const int tid = threadIdx.x;
  const int w = tid >> 6, l = tid & 63;
  const int wr = w >> 1, wc = w & 1;
  const int bm = blockIdx.x, bn = blockIdx.y;
  f32x4 acc[4][4] = {};
  const u16* Ab = A + (size_t)bm * 128 * K;
  const u16* Bb = B + (size_t)bn * 128 * K;
  const int lrow = l >> 2, lcol = (l & 3) * 8;

  for (int k0 = 0; k0 < K; k0 += 32) {
    __syncthreads();
#pragma unroll
    for (int i = 0; i < 2; ++i) {
      const int rbase = i * 64 + w * 16;
      async16(&As[rbase * 32], Ab + (size_t)(rbase + lrow) * K + k0 + lcol);
      async16(&Bs[rbase * 32], Bb + (size_t)(rbase + lrow) * K + k0 + lcol);
    }
    __syncthreads();
    bf16x8 af[4], bfv[4];
#pragma unroll
    for (int mi = 0; mi < 4; ++mi)
      af[mi] = *(const bf16x8*)&As[(wr * 64 + mi * 16 + (l & 15)) * 32 + (l >> 4) * 8];
#pragma unroll
    for (int ni = 0; ni < 4; ++ni)
      bfv[ni] = *(const bf16x8*)&Bs[(wc * 64 + ni * 16 + (l & 15)) * 32 + (l >> 4) * 8];
#pragma unroll
    for (int mi = 0; mi < 4; ++mi)
#pragma unroll
      for (int ni = 0; ni < 4; ++ni)
        acc[mi][ni] = __builtin_amdgcn_mfma_f32_16x16x32_bf16(af[mi], bfv[ni], acc[mi][ni], 0, 0, 0);
  }
#pragma unroll
  for (int mi = 0; mi < 4; ++mi)
#pragma unroll
    for (int ni = 0; ni < 4; ++ni)
#pragma unroll
      for (int r = 0; r < 4; ++r) {
        int row = bm * 128 + wr * 64 + mi * 16 + (l >> 4) * 4 + r;
        int col = bn * 128 + wc * 64 + ni * 16 + (l & 15);
        float v = acc[mi][ni][r];
        if (BF16OUT)
          ((u16*)Cv)[(size_t)row * N + col] = f2bf(v);
        else
          ((float*)Cv)[(size_t)row * N + col] = v;
      }
}

// ---------------- RoPE (in-place on bf16 buffer, layout [B*S][nh*128]) ----------------
__global__ __launch_bounds__(256) void rope_kernel(u16* __restrict__ buf,
                                                   const float* __restrict__ fc,
                                                   const float* __restrict__ fs,
                                                   const int* __restrict__ spp,
                                                   int nh, int total) {
  int t = blockIdx.x * 256 + threadIdx.x;
  if (t >= total) return;
  int i = t & 63;
  int h = (t >> 6) % nh;
  int s = ((t >> 6) / nh) % SEQ;
  int b = t / (64 * nh * SEQ);
  int pos = spp[0] + s;
  float c = fc[pos * 64 + i], sn = fs[pos * 64 + i];
  u16* p = buf + ((size_t)(b * SEQ + s) * nh + h) * HD + 2 * i;
  u32 both = *(u32*)p;
  float xr = bf2f((u16)(both & 0xffffu));
  float xi = bf2f((u16)(both >> 16));
  float orr = xr * c - xi * sn;
  float oi = xr * sn + xi * c;
  *(u32*)p = (u32)f2bf(orr) | ((u32)f2bf(oi) << 16);
}

// ---------------- Flash attention (causal, GQA), KVBLK=64, V^T in LDS ----------------
// K LDS layout: elem(row,col) at kswz(row,col); XOR-swizzled to kill the
// 16-lane same-column bank conflict on ds_read_b128 (G4).
__device__ __forceinline__ int kswz(int row, int colel) {
  int byte = (row << 8) + (colel << 1);
  byte ^= (row & 7) << 4;
  return byte >> 1;
}
// V^T LDS layout: Vt[d][kv], kv XOR-swizzled by d so (a) the 8-elem kv chunks
// stay contiguous (XOR is a multiple of 8) and (b) reads/writes spread banks.
__device__ __forceinline__ int vswz(int d, int kv) {
  return d * 64 + (kv ^ ((d & 7) << 3));
}

__global__ __launch_bounds__(256) void attn_kernel(const u16* __restrict__ qb,
                                                   const u16* __restrict__ kb,
                                                   const u16* __restrict__ vb,
                                                   u16* __restrict__ ob,
                                                   const int* __restrict__ spp) {
  // bijective XCD chunking (2048 % 8 == 0) + reversed qt (heavy tiles first)
  const int wg = (blockIdx.x & 7) * 256 + (blockIdx.x >> 3);
  const int qt = 31 - (wg & 31);
  const int h = (wg >> 5) & 31;
  const int b = wg >> 10;
  const int kvh = h >> 2;
  const int tid = threadIdx.x, w = tid >> 6, l = tid & 63;
  const int sp = spp[0];
  __shared__ __align__(16) u16 Kl[64 * 128];
  __shared__ __align__(16) u16 Vt[128 * 64];
  __shared__ __align__(16) u16 Pl[4][16 * 72];
  const int qs = qt * 64;
  const int wq0 = qs + w * 16;

  bf16x8 qf[4];
  const u16* qrow = qb + (size_t)(b * SEQ + wq0 + (l & 15)) * DIM + h * HD;
#pragma unroll
  for (int kk = 0; kk < 4; ++kk)
    qf[kk] = *(const bf16x8*)(qrow + kk * 32 + (l >> 4) * 8);

  f32x4 acc[8] = {};
  float mst[4] = {-1e30f, -1e30f, -1e30f, -1e30f};
  float lst[4] = {0.f, 0.f, 0.f, 0.f};
  const int nt = qt + 1;
  const size_t kvbase = (size_t)b * SEQ * (NKV * HD) + kvh * HD;

  for (int t = 0; t < nt; ++t) {
    const int t0 = t * 64;
    __syncthreads();
    // ---- K stage: global_load_lds, linear LDS dest, inverse-swizzled source.
    // LDS 16B-granule g holds K[row=g>>4][col=((g&15)^(row&7))*8 ..+8].
#pragma unroll
    for (int c0 = 0; c0 < 4; ++c0) {
      int g = c0 * 256 + tid;
      int row = g >> 4;
      int col = ((g & 15) ^ (row & 7)) * 8;
      async16(&Kl[g * 8], kb + kvbase + (size_t)(t0 + row) * (NKV * HD) + col);
    }
    // ---- V stage: reg transpose into Vt[d][kv]
#pragma unroll
    for (int c0 = 0; c0 < 4; ++c0) {
      int g = c0 * 256 + tid;
      int row = g >> 4, col = (g & 15) * 8;
      union { int4 i; u16 u[8]; } vv;
      vv.i = *(const int4*)(vb + kvbase + (size_t)(t0 + row) * (NKV * HD) + col);
#pragma unroll
      for (int j = 0; j < 8; ++j) Vt[vswz(col + j, row)] = vv.u[j];
    }
    __syncthreads();

    // ---- QK^T: S[16q x 64kv] per wave
    float sv[4][4];
#pragma unroll
    for (int tt = 0; tt < 4; ++tt) {
      f32x4 sacc = {};
#pragma unroll
      for (int kk = 0; kk < 4; ++kk) {
        bf16x8 kf = *(const bf16x8*)&Kl[kswz(tt * 16 + (l & 15), kk * 32 + (l >> 4) * 8)];
        sacc = __builtin_amdgcn_mfma_f32_16x16x32_bf16(qf[kk], kf, sacc, 0, 0, 0);
      }
#pragma unroll
      for (int r = 0; r < 4; ++r) sv[tt][r] = sacc[r] * 0.08838834764831845f;
    }
    if (t == nt - 1) {  // diagonal tile: apply causal mask
#pragma unroll
      for (int tt = 0; tt < 4; ++tt)
#pragma unroll
        for (int r = 0; r < 4; ++r) {
          int qrow_s = wq0 + (l >> 4) * 4 + r;
          int tg = t0 + tt * 16 + (l & 15);
          if (tg > sp + qrow_s) sv[tt][r] = -1e9f;
        }
    }
    // ---- online softmax (rows spread over 16 lanes: shfl_xor 1,2,4,8)
    float pm[4];
#pragma unroll
    for (int r = 0; r < 4; ++r)
      pm[r] = fmaxf(fmaxf(sv[0][r], sv[1][r]), fmaxf(sv[2][r], sv[3][r]));
#pragma unroll
    for (int off = 1; off < 16; off <<= 1)
#pragma unroll
      for (int r = 0; r < 4; ++r) pm[r] = fmaxf(pm[r], __shfl_xor(pm[r], off));

    float esc[4];
#pragma unroll
    for (int r = 0; r < 4; ++r) {
      float mn = fmaxf(mst[r], pm[r]);
      esc[r] = __expf(mst[r] - mn);
      mst[r] = mn;
    }
    float p[4][4];
#pragma unroll
    for (int tt = 0; tt < 4; ++tt)
#pragma unroll
      for (int r = 0; r < 4; ++r) p[tt][r] = __expf(sv[tt][r] - mst[r]);
    float rs[4];
#pragma unroll
    for (int r = 0; r < 4; ++r) rs[r] = (p[0][r] + p[1][r]) + (p[2][r] + p[3][r]);
#pragma unroll
    for (int off = 1; off < 16; off <<= 1)
#pragma unroll
      for (int r = 0; r < 4; ++r) rs[r] += __shfl_xor(rs[r], off);
#pragma unroll
    for (int r = 0; r < 4; ++r) lst[r] = lst[r] * esc[r] + rs[r];
#pragma unroll
    for (int dc = 0; dc < 8; ++dc)
#pragma unroll
      for (int r = 0; r < 4; ++r) acc[dc][r] *= esc[r];

    // ---- P roundtrip through per-wave LDS (C-layout -> A-layout remap)
#pragma unroll
    for (int tt = 0; tt < 4; ++tt)
#pragma unroll
      for (int r = 0; r < 4; ++r)
        Pl[w][((l >> 4) * 4 + r) * 72 + tt * 16 + (l & 15)] = f2bf(p[tt][r]);
    bf16x8 pf[2];
#pragma unroll
    for (int kk2 = 0; kk2 < 2; ++kk2)
      pf[kk2] = *(const bf16x8*)&Pl[w][(l & 15) * 72 + kk2 * 32 + (l >> 4) * 8];

    // ---- PV: vectorized B-frags from Vt
#pragma unroll
    for (int dc = 0; dc < 8; ++dc) {
#pragma unroll
      for (int kk2 = 0; kk2 < 2; ++kk2) {
        int d = dc * 16 + (l & 15);
        bf16x8 vf = *(const bf16x8*)&Vt[vswz(d, kk2 * 32 + (l >> 4) * 8)];
        acc[dc] = __builtin_amdgcn_mfma_f32_16x16x32_bf16(pf[kk2], vf, acc[dc], 0, 0, 0);
      }
    }
  }
  // epilogue
#pragma unroll
  for (int r = 0; r < 4; ++r) {
    float inv = 1.0f / lst[r];
    size_t rowoff = (size_t)(b * SEQ + wq0 + (l >> 4) * 4 + r) * DIM + h * HD;
#pragma unroll
    for (int dc = 0; dc < 8; ++dc)
      ob[rowoff + dc * 16 + (l & 15)] = f2bf(acc[dc][r] * inv);
  }
}

extern "C" void kernel_launch(void* const* d_in, const int* in_sizes, int n_in,
                              void* d_out, int out_size, void* d_ws, size_t ws_size,
                              hipStream_t stream) {
  (void)in_sizes; (void)n_in; (void)out_size; (void)ws_size;
  const float* x  = (const float*)d_in[0];
  const float* wq = (const float*)d_in[1];
  const float* wk = (const float*)d_in[2];
  const float* wv = (const float*)d_in[3];
  const float* wo = (const float*)d_in[4];
  const float* fc = (const float*)d_in[5];
  const float* fs = (const float*)d_in[6];
  const int* sp   = (const int*)d_in[9];

  char* ws = (char*)d_ws;
  size_t off = 0;
  auto alloc = [&](size_t bytes) {
    void* p = ws + off;
    off += (bytes + 255) & ~(size_t)255;
    return p;
  };
  u16* xb   = (u16*)alloc(16777216ull * 2);  // x bf16 (also reused as attn-out)
  u16* wqb  = (u16*)alloc(16777216ull * 2);
  u16* wkb  = (u16*)alloc(4194304ull * 2);
  u16* wvb  = (u16*)alloc(4194304ull * 2);
  u16* wob  = (u16*)alloc(16777216ull * 2);
  u16* qbuf = (u16*)alloc(16777216ull * 2);
  u16* kbuf = (u16*)alloc(4194304ull * 2);
  u16* vbuf = (u16*)alloc(4194304ull * 2);
  u16* abuf = xb;  // alias: xb dead after QKV GEMMs

  auto cast = [&](const float* in, u16* out, size_t n) {
    int n4 = (int)(n / 4);
    cast_kernel<<<(n4 + 255) / 256, 256, 0, stream>>>(in, out, n4);
  };
  cast(x,  xb,  16777216ull);
  cast(wq, wqb, 16777216ull);
  cast(wk, wkb, 4194304ull);
  cast(wv, wvb, 4194304ull);
  cast(wo, wob, 16777216ull);

  gemm_bt<true><<<dim3(32, 32), 256, 0, stream>>>(xb, wqb, qbuf, 4096, 4096, 4096);
  gemm_bt<true><<<dim3(32, 8), 256, 0, stream>>>(xb, wkb, kbuf, 4096, 1024, 4096);
  gemm_bt<true><<<dim3(32, 8), 256, 0, stream>>>(xb, wvb, vbuf, 4096, 1024, 4096);

  rope_kernel<<<8388608 / 256, 256, 0, stream>>>(qbuf, fc, fs, sp, NH, 8388608);
  rope_kernel<<<2097152 / 256, 256, 0, stream>>>(kbuf, fc, fs, sp, NKV, 2097152);

  attn_kernel<<<2048, 256, 0, stream>>>(qbuf, kbuf, vbuf, abuf, sp);

  gemm_bt<false><<<dim3(32, 32), 256, 0, stream>>>(abuf, wob, d_out, 4096, 4096, 4096);
}